// Round 7
// baseline (17213.208 us; speedup 1.0000x reference)
//
#include <hip/hip_runtime.h>

typedef __attribute__((ext_vector_type(8))) _Float16 f16x8;
typedef __attribute__((ext_vector_type(4))) float f32x4;
typedef unsigned long long ull;

#define T_STEPS 1024
#define BATCH   128
#define FDIM    128
#define UDIM    256
#define GCOLS   1024   // 4*U
#define ROWS    16     // batch rows per group
#define HWPR    128    // 64-bit h words per row (256 fp16 / 2)
#define HST     264    // hs row stride (f16): 528B = 33 x 16B-slots -> conflict-free b128
#define MAGICW  0xDEADBEEFCAFEF00Dull

// h exchange: tagged words {lo32: 2 fp16, hi32: step tag}, double-buffered.
// Pure groups (validated same-L2): plain stores + sc0 loads through the shared
// XCD L2 (~200cy). Otherwise/on abort: relaxed agent-scope atomics (L3 path).

__device__ __forceinline__ ull load1_sc0(const ull* p) {
    ull v;
    asm volatile("global_load_dwordx2 %0, %1, off sc0\n\t"
                 "s_waitcnt vmcnt(0)"
                 : "=&v"(v) : "v"(p) : "memory");
    return v;
}

__device__ __forceinline__ void load8_sc0(const ull* p, ull* v) {
    asm volatile(
        "global_load_dwordx2 %0, %8, off sc0\n\t"
        "global_load_dwordx2 %1, %8, off offset:8 sc0\n\t"
        "global_load_dwordx2 %2, %8, off offset:16 sc0\n\t"
        "global_load_dwordx2 %3, %8, off offset:24 sc0\n\t"
        "global_load_dwordx2 %4, %8, off offset:32 sc0\n\t"
        "global_load_dwordx2 %5, %8, off offset:40 sc0\n\t"
        "global_load_dwordx2 %6, %8, off offset:48 sc0\n\t"
        "global_load_dwordx2 %7, %8, off offset:56 sc0\n\t"
        "s_waitcnt vmcnt(0)"
        : "=&v"(v[0]), "=&v"(v[1]), "=&v"(v[2]), "=&v"(v[3]),
          "=&v"(v[4]), "=&v"(v[5]), "=&v"(v[6]), "=&v"(v[7])
        : "v"(p)
        : "memory");
}

__global__ __launch_bounds__(256, 1)
void lstm_scan_kernel(const float* __restrict__ xg, const float* __restrict__ Wg,
                      const float* __restrict__ Rg, const float* __restrict__ bg_,
                      float* __restrict__ outg, unsigned* __restrict__ ctrl,
                      ull* __restrict__ tst, ull* __restrict__ hbuf)
{
    __shared__ _Float16 hs[2][ROWS][HST];
    __shared__ int sh_pure;
    __shared__ int sh_abort;

    const int tid  = threadIdx.x;
    const int lane = tid & 63;
    const int wv   = tid >> 6;
    const int bgi  = blockIdx.x & 7;
    const int ngi  = blockIdx.x >> 3;
    const int r0   = bgi * ROWS;
    const int u0   = ngi * 32;
    const int lj   = lane & 15;
    const int lg   = lane >> 4;
    const int hb   = lj >> 3;
    const int uc   = u0 + wv * 8 + (lj & 7);

    if (tid == 0) sh_abort = 0;

    // ---- validation handshake: is this group on one L2? ----
    if (tid == 0) {
        ull* tw = tst + bgi * 16;   // 128B apart per group
        if (ngi == 0)
            __hip_atomic_store(tw, MAGICW, __ATOMIC_RELAXED, __HIP_MEMORY_SCOPE_WORKGROUP);
        bool ok = false;
        for (int it = 0; it < (1 << 14); ++it)
            if (load1_sc0(tw) == MAGICW) { ok = true; break; }
        if (ok)
            __hip_atomic_fetch_add(&ctrl[bgi], 1u, __ATOMIC_RELAXED, __HIP_MEMORY_SCOPE_AGENT);
        __hip_atomic_fetch_add(&ctrl[8], 1u, __ATOMIC_RELEASE, __HIP_MEMORY_SCOPE_AGENT);
        while (__hip_atomic_load(&ctrl[8], __ATOMIC_ACQUIRE, __HIP_MEMORY_SCOPE_AGENT) < 64u) {}
        sh_pure = (__hip_atomic_load(&ctrl[bgi], __ATOMIC_RELAXED, __HIP_MEMORY_SCOPE_AGENT) == 8u) ? 1 : 0;
    }
    __syncthreads();
    int purerun = sh_pure;

    // ---- one-time: B fragments (W;R combined, fp16) in registers ----
    f16x8 bfr[2][12];
#pragma unroll
    for (int nt = 0; nt < 2; ++nt) {
        const int col = (nt * 2 + hb) * 256 + uc;
#pragma unroll
        for (int ks = 0; ks < 12; ++ks) {
            f16x8 v;
#pragma unroll
            for (int i = 0; i < 8; ++i) {
                const int k = ks * 32 + lg * 8 + i;
                const float w = (k < FDIM) ? Wg[k * GCOLS + col]
                                           : Rg[(k - FDIM) * GCOLS + col];
                v[i] = (_Float16)w;
            }
            bfr[nt][ks] = v;
        }
    }

    const float b_i = bg_[uc];
    const float b_f = bg_[256 + uc];
    const float b_g = bg_[512 + uc];
    const float b_o = bg_[768 + uc];

    const int row0 = lg * 4 + hb * 2;
    float cc0 = 0.f, cc1 = 0.f;
    ull shw[2][2] = {{0ull, 0ull}, {0ull, 0ull}};   // last words stored per buffer

    const int xrw = tid & 15;            // row this thread polls/stages
    const int c16 = tid >> 4;            // 16-fp16 chunk (= 8 words)
    const size_t hrd = (size_t)(r0 + xrw) * HWPR + c16 * 8;
    const float* const xrowp = xg + (size_t)(r0 + lj) * T_STEPS * FDIM + lg * 8;

    // zero hs[0] (t==0 uses h = 0; never reads hbuf)
    for (int i = tid; i < ROWS * HST; i += 256)
        (&hs[0][0][0])[i] = (_Float16)0.f;

    // prefetch x(0)
    f32x4 xn[8];
#pragma unroll
    for (int ks = 0; ks < 4; ++ks) {
        xn[2 * ks]     = *(const f32x4*)(xrowp + ks * 32);
        xn[2 * ks + 1] = *(const f32x4*)(xrowp + ks * 32 + 4);
    }

    for (int t = 0; t < T_STEPS; ++t) {
        const int p = t & 1;

        if (t > 0) {
            const ull* hp = hbuf + (size_t)p * BATCH * HWPR + hrd;
            ull hv[8];
            const unsigned tg = (unsigned)t;
            bool agent_fin = (purerun == 0);
            if (purerun) {
                int spins = 0;
                load8_sc0(hp, hv);
                while (true) {
                    bool ok = true;
#pragma unroll
                    for (int j = 0; j < 8; ++j) ok &= ((unsigned)(hv[j] >> 32) == tg);
                    if (ok) break;
                    ++spins;
                    if ((spins & 255) == 0) {
                        if (spins > (1 << 15))
                            __hip_atomic_store(&ctrl[16 + bgi], 1u, __ATOMIC_RELAXED,
                                               __HIP_MEMORY_SCOPE_AGENT);
                        if (__hip_atomic_load(&ctrl[16 + bgi], __ATOMIC_RELAXED,
                                              __HIP_MEMORY_SCOPE_AGENT) != 0u) {
                            agent_fin = true; sh_abort = 1; break;
                        }
                    }
                    load8_sc0(hp, hv);
                }
            }
            if (agent_fin) {   // safe path: agent-scope (L3) polling
                while (true) {
#pragma unroll
                    for (int j = 0; j < 8; ++j)
                        hv[j] = __hip_atomic_load(hp + j, __ATOMIC_RELAXED,
                                                  __HIP_MEMORY_SCOPE_AGENT);
                    bool ok = true;
#pragma unroll
                    for (int j = 0; j < 8; ++j) ok &= ((unsigned)(hv[j] >> 32) == tg);
                    if (ok) break;
                }
            }
            // stage h -> LDS (fp16 payloads in word lo32s)
            uint4 a4, b4;
            a4.x = (unsigned)hv[0]; a4.y = (unsigned)hv[1];
            a4.z = (unsigned)hv[2]; a4.w = (unsigned)hv[3];
            b4.x = (unsigned)hv[4]; b4.y = (unsigned)hv[5];
            b4.z = (unsigned)hv[6]; b4.w = (unsigned)hv[7];
            *(uint4*)&hs[p][xrw][c16 * 16]     = a4;
            *(uint4*)&hs[p][xrw][c16 * 16 + 8] = b4;
        }
        __syncthreads();

        // abort propagation: demote uniformly, re-publish shadows agent-scope
        if (sh_abort && purerun) {
            purerun = 0;
            if (!(lj & 1)) {
                ull* h0 = hbuf + (size_t)(r0 + row0) * HWPR + (uc >> 1);
#pragma unroll
                for (int b = 0; b < 2; ++b) {
                    __hip_atomic_store(h0 + (size_t)b * BATCH * HWPR, shw[b][0],
                                       __ATOMIC_RELAXED, __HIP_MEMORY_SCOPE_AGENT);
                    __hip_atomic_store(h0 + (size_t)b * BATCH * HWPR + HWPR, shw[b][1],
                                       __ATOMIC_RELAXED, __HIP_MEMORY_SCOPE_AGENT);
                }
            }
        }

        // convert current x fragments, then prefetch x(t+1)
        f16x8 af[4];
#pragma unroll
        for (int ks = 0; ks < 4; ++ks) {
            const f32x4 lo = xn[2 * ks], hi = xn[2 * ks + 1];
            f16x8 a;
#pragma unroll
            for (int i = 0; i < 4; ++i) { a[i] = (_Float16)lo[i]; a[4 + i] = (_Float16)hi[i]; }
            af[ks] = a;
        }
        const int tn = (t + 1 < T_STEPS) ? (t + 1) : t;
        const float* xpn = xrowp + (size_t)tn * FDIM;
#pragma unroll
        for (int ks = 0; ks < 4; ++ks) {
            xn[2 * ks]     = *(const f32x4*)(xpn + ks * 32);
            xn[2 * ks + 1] = *(const f32x4*)(xpn + ks * 32 + 4);
        }

        // z = [x_t | h] @ [W;R]: 12 K-steps, dual chains, 2 n-tiles per wave
        f32x4 a0e = {0,0,0,0}, a0o = {0,0,0,0}, a1e = {0,0,0,0}, a1o = {0,0,0,0};
#pragma unroll
        for (int ks = 0; ks < 12; ++ks) {
            const f16x8 a = (ks < 4) ? af[ks]
                : *(const f16x8*)&hs[p][lj][(ks - 4) * 32 + lg * 8];
            if (ks & 1) {
                a0o = __builtin_amdgcn_mfma_f32_16x16x32_f16(a, bfr[0][ks], a0o, 0, 0, 0);
                a1o = __builtin_amdgcn_mfma_f32_16x16x32_f16(a, bfr[1][ks], a1o, 0, 0, 0);
            } else {
                a0e = __builtin_amdgcn_mfma_f32_16x16x32_f16(a, bfr[0][ks], a0e, 0, 0, 0);
                a1e = __builtin_amdgcn_mfma_f32_16x16x32_f16(a, bfr[1][ks], a1e, 0, 0, 0);
            }
        }
        const f32x4 z0 = a0e + a0o;   // gates i,f
        const f32x4 z1 = a1e + a1o;   // gates g,o

        // intra-wave gate exchange: partner lane^8 holds the other gate
        float s0[4], s1[4];
#pragma unroll
        for (int e = 0; e < 4; ++e) {
            s0[e] = __shfl_xor(z0[e], 8);
            s1[e] = __shfl_xor(z1[e], 8);
        }
        float zi0 = hb ? s0[2] : z0[0];
        float zi1 = hb ? s0[3] : z0[1];
        float zf0 = hb ? z0[2] : s0[0];
        float zf1 = hb ? z0[3] : s0[1];
        float zg0 = hb ? s1[2] : z1[0];
        float zg1 = hb ? s1[3] : z1[1];
        float zo0 = hb ? z1[2] : s1[0];
        float zo1 = hb ? z1[3] : s1[1];

        zi0 += b_i; zi1 += b_i; zf0 += b_f; zf1 += b_f;
        zg0 += b_g; zg1 += b_g; zo0 += b_o; zo1 += b_o;

        const float i0 = 1.f / (1.f + __expf(-zi0));
        const float f0 = 1.f / (1.f + __expf(-zf0));
        const float o0 = 1.f / (1.f + __expf(-zo0));
        const float i1 = 1.f / (1.f + __expf(-zi1));
        const float f1 = 1.f / (1.f + __expf(-zf1));
        const float o1 = 1.f / (1.f + __expf(-zo1));
        cc0 = f0 * cc0 + i0 * zg0;     // g is LINEAR (activation=None)
        cc1 = f1 * cc1 + i1 * zg1;
        const float h0v = o0 * cc0;    // h = o * c (no tanh on cell)
        const float h1v = o1 * cc1;

        if (t == T_STEPS - 1) {
            float* op = outg + (size_t)(r0 + row0) * UDIM + uc;
            op[0]    = tanhf(h0v);     // post-hoc tanh on last h
            op[UDIM] = tanhf(h1v);
        } else {
            const float n0 = __shfl_xor(h0v, 1);
            const float n1 = __shfl_xor(h1v, 1);
            if (!(lj & 1)) {
                union { _Float16 h[2]; unsigned lo; } pa, pb;
                pa.h[0] = (_Float16)h0v; pa.h[1] = (_Float16)n0;
                pb.h[0] = (_Float16)h1v; pb.h[1] = (_Float16)n1;
                const ull tagw = (ull)(unsigned)(t + 1) << 32;
                const ull w0 = tagw | pa.lo, w1 = tagw | pb.lo;
                const int pb2 = p ^ 1;
                ull* hw = hbuf + (size_t)pb2 * BATCH * HWPR
                          + (size_t)(r0 + row0) * HWPR + (uc >> 1);
                shw[pb2][0] = w0; shw[pb2][1] = w1;
                if (purerun) {   // plain stores: stay in the shared XCD L2
                    __hip_atomic_store(hw,        w0, __ATOMIC_RELAXED, __HIP_MEMORY_SCOPE_WORKGROUP);
                    __hip_atomic_store(hw + HWPR, w1, __ATOMIC_RELAXED, __HIP_MEMORY_SCOPE_WORKGROUP);
                } else {
                    __hip_atomic_store(hw,        w0, __ATOMIC_RELAXED, __HIP_MEMORY_SCOPE_AGENT);
                    __hip_atomic_store(hw + HWPR, w1, __ATOMIC_RELAXED, __HIP_MEMORY_SCOPE_AGENT);
                }
            }
        }
    }

    // flush dirty L2 lines (h words, test word, outputs) so no stale tagged
    // data survives into the next graph replay.
    __threadfence();
}

extern "C" void kernel_launch(void* const* d_in, const int* in_sizes, int n_in,
                              void* d_out, int out_size, void* d_ws, size_t ws_size,
                              hipStream_t stream) {
    const float* x = (const float*)d_in[0];   // [128,1024,128]
    const float* W = (const float*)d_in[1];   // [128,1024]
    const float* R = (const float*)d_in[2];   // [256,1024]
    const float* b = (const float*)d_in[3];   // [1024]
    float* out = (float*)d_out;               // [128,256]

    unsigned char* ws = (unsigned char*)d_ws;
    unsigned* ctrl = (unsigned*)ws;           // votes[8], arr@8, abort[8]@16
    ull* tst  = (ull*)(ws + 4096);            // per-group test words
    ull* hbuf = (ull*)(ws + 8192);            // [2][128][128] tagged words

    const size_t clr = 8192 + (size_t)2 * BATCH * HWPR * sizeof(ull);
    hipMemsetAsync(d_ws, 0, clr, stream);

    hipLaunchKernelGGL(lstm_scan_kernel, dim3(64), dim3(256), 0, stream,
                       x, W, R, b, out, ctrl, tst, hbuf);
}

// Round 8
// 3290.441 us; speedup vs baseline: 5.2313x; 5.2313x over previous
//
#include <hip/hip_runtime.h>

typedef __attribute__((ext_vector_type(8))) _Float16 f16x8;
typedef __attribute__((ext_vector_type(4))) float f32x4;
typedef unsigned long long ull;

#define T_STEPS 1024
#define BATCH   128
#define FDIM    128
#define UDIM    256
#define GCOLS   1024   // 4*U
#define ROWS    16     // batch rows per group
#define HWPR    128    // 64-bit h words per row (256 fp16 / 2)
#define HST     264    // hs row stride (f16): 528B -> benign LDS banking

// Protocol (round-3, proven): h exchange as tagged 64-bit words
// {lo32: 2 fp16, hi32: step tag}, double-buffered in workspace, relaxed
// agent-scope atomics (coherence point = memory-side Infinity Cache).
// Structure (round-5, proven): each wave owns all 4 gates for its 8 u-cols;
// gate combine is intra-wave shfl_xor -> z never touches LDS, ONE barrier/step.

__global__ __launch_bounds__(256, 1)
void lstm_scan_kernel(const float* __restrict__ xg, const float* __restrict__ Wg,
                      const float* __restrict__ Rg, const float* __restrict__ bg_,
                      float* __restrict__ outg, ull* __restrict__ hbuf)
{
    __shared__ _Float16 hs[2][ROWS][HST];

    const int tid  = threadIdx.x;
    const int lane = tid & 63;
    const int wv   = tid >> 6;
    const int bgi  = blockIdx.x & 7;    // batch group
    const int ngi  = blockIdx.x >> 3;   // u-slice group
    const int r0   = bgi * ROWS;
    const int u0   = ngi * 32;
    const int lj   = lane & 15;         // MFMA m/n index
    const int lg   = lane >> 4;         // MFMA k-group
    const int hb   = lj >> 3;           // gate-half owner bit
    const int uc   = u0 + wv * 8 + (lj & 7);   // this lane's u column

    // ---- one-time: B fragments (W;R combined, fp16) in registers ----
    // n-tile nt covers gates {2nt, 2nt+1}: lane col = gate (nt*2+hb), ucol uc.
    f16x8 bfr[2][12];
#pragma unroll
    for (int nt = 0; nt < 2; ++nt) {
        const int col = (nt * 2 + hb) * 256 + uc;
#pragma unroll
        for (int ks = 0; ks < 12; ++ks) {
            f16x8 v;
#pragma unroll
            for (int i = 0; i < 8; ++i) {
                const int k = ks * 32 + lg * 8 + i;
                const float w = (k < FDIM) ? Wg[k * GCOLS + col]
                                           : Rg[(k - FDIM) * GCOLS + col];
                v[i] = (_Float16)w;
            }
            bfr[nt][ks] = v;
        }
    }

    const float b_i = bg_[uc];
    const float b_f = bg_[256 + uc];
    const float b_g = bg_[512 + uc];
    const float b_o = bg_[768 + uc];

    const int row0 = lg * 4 + hb * 2;   // first of this lane's 2 output rows
    float cc0 = 0.f, cc1 = 0.f;

    // poll/stage roles: thread (prow, pw0) owns 8 words of row prow
    const int prow = tid >> 4;
    const int pw0  = (tid & 15) * 8;
    const size_t hrd = (size_t)(r0 + prow) * HWPR + pw0;
    const float* const xrowp = xg + (size_t)(r0 + lj) * T_STEPS * FDIM + lg * 8;

    // t==0 uses h = 0: zero hs[0], never read hbuf at t==0
    for (int i = tid; i < ROWS * HST; i += 256)
        (&hs[0][0][0])[i] = (_Float16)0.f;

    // prefetch x(0)
    f32x4 xn[8];
#pragma unroll
    for (int ks = 0; ks < 4; ++ks) {
        xn[2 * ks]     = *(const f32x4*)(xrowp + ks * 32);
        xn[2 * ks + 1] = *(const f32x4*)(xrowp + ks * 32 + 4);
    }

    for (int t = 0; t < T_STEPS; ++t) {
        const int p = t & 1;

        if (t > 0) {
            // ---- poll this thread's 8 tagged words (no intra-WG redundancy) ----
            const ull* hp = hbuf + (size_t)p * BATCH * HWPR + hrd;
            ull hv[8];
            const unsigned tg = (unsigned)t;
            while (true) {
#pragma unroll
                for (int j = 0; j < 8; ++j)
                    hv[j] = __hip_atomic_load(hp + j, __ATOMIC_RELAXED,
                                              __HIP_MEMORY_SCOPE_AGENT);
                bool ok = true;
#pragma unroll
                for (int j = 0; j < 8; ++j)
                    ok &= ((unsigned)(hv[j] >> 32) == tg);
                if (ok) break;
            }
            // stage h -> LDS (fp16 payloads live in the word lo32s)
            uint4 a4, b4;
            a4.x = (unsigned)hv[0]; a4.y = (unsigned)hv[1];
            a4.z = (unsigned)hv[2]; a4.w = (unsigned)hv[3];
            b4.x = (unsigned)hv[4]; b4.y = (unsigned)hv[5];
            b4.z = (unsigned)hv[6]; b4.w = (unsigned)hv[7];
            *(uint4*)&hs[p][prow][pw0 * 2]     = a4;
            *(uint4*)&hs[p][prow][pw0 * 2 + 8] = b4;
        }
        __syncthreads();   // the ONLY barrier per step (hs double-buffered)

        // convert x(t) fragments, then prefetch x(t+1)
        f16x8 af[4];
#pragma unroll
        for (int ks = 0; ks < 4; ++ks) {
            const f32x4 lo = xn[2 * ks], hi = xn[2 * ks + 1];
            f16x8 a;
#pragma unroll
            for (int i = 0; i < 4; ++i) { a[i] = (_Float16)lo[i]; a[4 + i] = (_Float16)hi[i]; }
            af[ks] = a;
        }
        const int tn = (t + 1 < T_STEPS) ? (t + 1) : t;
        const float* xpn = xrowp + (size_t)tn * FDIM;
#pragma unroll
        for (int ks = 0; ks < 4; ++ks) {
            xn[2 * ks]     = *(const f32x4*)(xpn + ks * 32);
            xn[2 * ks + 1] = *(const f32x4*)(xpn + ks * 32 + 4);
        }

        // z = [x_t | h] @ [W;R]: 12 K-steps, dual chains, 2 n-tiles per wave
        f32x4 a0e = {0,0,0,0}, a0o = {0,0,0,0}, a1e = {0,0,0,0}, a1o = {0,0,0,0};
#pragma unroll
        for (int ks = 0; ks < 12; ++ks) {
            const f16x8 a = (ks < 4) ? af[ks]
                : *(const f16x8*)&hs[p][lj][(ks - 4) * 32 + lg * 8];
            if (ks & 1) {
                a0o = __builtin_amdgcn_mfma_f32_16x16x32_f16(a, bfr[0][ks], a0o, 0, 0, 0);
                a1o = __builtin_amdgcn_mfma_f32_16x16x32_f16(a, bfr[1][ks], a1o, 0, 0, 0);
            } else {
                a0e = __builtin_amdgcn_mfma_f32_16x16x32_f16(a, bfr[0][ks], a0e, 0, 0, 0);
                a1e = __builtin_amdgcn_mfma_f32_16x16x32_f16(a, bfr[1][ks], a1e, 0, 0, 0);
            }
        }
        const f32x4 z0 = a0e + a0o;   // gates i,f
        const f32x4 z1 = a1e + a1o;   // gates g,o

        // intra-wave gate exchange: partner lane^8 holds the other gate
        float s0[4], s1[4];
#pragma unroll
        for (int e = 0; e < 4; ++e) {
            s0[e] = __shfl_xor(z0[e], 8);
            s1[e] = __shfl_xor(z1[e], 8);
        }
        float zi0 = hb ? s0[2] : z0[0];
        float zi1 = hb ? s0[3] : z0[1];
        float zf0 = hb ? z0[2] : s0[0];
        float zf1 = hb ? z0[3] : s0[1];
        float zg0 = hb ? s1[2] : z1[0];
        float zg1 = hb ? s1[3] : z1[1];
        float zo0 = hb ? z1[2] : s1[0];
        float zo1 = hb ? z1[3] : s1[1];

        zi0 += b_i; zi1 += b_i; zf0 += b_f; zf1 += b_f;
        zg0 += b_g; zg1 += b_g; zo0 += b_o; zo1 += b_o;

        const float i0 = 1.f / (1.f + __expf(-zi0));
        const float f0 = 1.f / (1.f + __expf(-zf0));
        const float o0 = 1.f / (1.f + __expf(-zo0));
        const float i1 = 1.f / (1.f + __expf(-zi1));
        const float f1 = 1.f / (1.f + __expf(-zf1));
        const float o1 = 1.f / (1.f + __expf(-zo1));
        cc0 = f0 * cc0 + i0 * zg0;     // g is LINEAR (activation=None)
        cc1 = f1 * cc1 + i1 * zg1;
        const float h0v = o0 * cc0;    // h = o * c (no tanh on cell)
        const float h1v = o1 * cc1;

        if (t == T_STEPS - 1) {
            float* op = outg + (size_t)(r0 + row0) * UDIM + uc;
            op[0]    = tanhf(h0v);     // post-hoc tanh on last h
            op[UDIM] = tanhf(h1v);
        } else {
            // publish: pack neighbor ucol (lane^1), even lanes store 2 words
            const float n0 = __shfl_xor(h0v, 1);
            const float n1 = __shfl_xor(h1v, 1);
            if (!(lj & 1)) {
                union { _Float16 h[2]; unsigned lo; } pa, pb;
                pa.h[0] = (_Float16)h0v; pa.h[1] = (_Float16)n0;
                pb.h[0] = (_Float16)h1v; pb.h[1] = (_Float16)n1;
                const ull tagw = (ull)(unsigned)(t + 1) << 32;
                ull* hw = hbuf + (size_t)(p ^ 1) * BATCH * HWPR
                          + (size_t)(r0 + row0) * HWPR + (uc >> 1);
                __hip_atomic_store(hw,        tagw | pa.lo,
                                   __ATOMIC_RELAXED, __HIP_MEMORY_SCOPE_AGENT);
                __hip_atomic_store(hw + HWPR, tagw | pb.lo,
                                   __ATOMIC_RELAXED, __HIP_MEMORY_SCOPE_AGENT);
            }
        }
    }
}

extern "C" void kernel_launch(void* const* d_in, const int* in_sizes, int n_in,
                              void* d_out, int out_size, void* d_ws, size_t ws_size,
                              hipStream_t stream) {
    const float* x = (const float*)d_in[0];   // [128,1024,128]
    const float* W = (const float*)d_in[1];   // [128,1024]
    const float* R = (const float*)d_in[2];   // [256,1024]
    const float* b = (const float*)d_in[3];   // [1024]
    float* out = (float*)d_out;               // [128,256]

    ull* hbuf = (ull*)d_ws;                   // [2][128][128] tagged words

    // zero both buffers every launch (kills stale tags from prior replays;
    // t==0 never reads hbuf, so tag-0 contents are irrelevant but clean)
    const size_t clr = (size_t)2 * BATCH * HWPR * sizeof(ull);
    hipMemsetAsync(d_ws, 0, clr, stream);

    hipLaunchKernelGGL(lstm_scan_kernel, dim3(64), dim3(256), 0, stream,
                       x, W, R, b, out, hbuf);
}

// Round 9
// 2073.425 us; speedup vs baseline: 8.3018x; 1.5870x over previous
//
#include <hip/hip_runtime.h>

typedef __attribute__((ext_vector_type(8))) _Float16 f16x8;
typedef __attribute__((ext_vector_type(4))) float f32x4;
typedef __attribute__((ext_vector_type(4))) unsigned u32x4;
typedef unsigned long long ull;

#define T_STEPS 1024
#define BATCH   128
#define FDIM    128
#define UDIM    256
#define GCOLS   1024   // 4*U
#define NGRP    8      // WGs per batch-group (u-split)
#define ROWS    16     // batch rows per WG
#define USL     32     // u columns per WG
#define KSTEPS  12     // 384 / 32
#define HWPR    128    // h words per row (256 fp16 / 2)
#define XST     136    // x stage row stride (f16), 128+8 pad
#define HST     264    // h stage row stride (f16), 256+8 pad
#define ZST     24     // z_lds inner stride (f32), 16+8 pad (keeps 16B align)

// Bulk fetch of 8 tagged words in one round trip (device-coherent flags).
// If sc0/sc1 semantics ever read stale data, the caller's verify loop falls
// back to builtin agent-scope atomic loads -> behavior degrades to round-3,
// never hangs.
__device__ __forceinline__ void load_w8_asm(const ull* p, ull* v) {
    u32x4 a, b, c, d;
    asm volatile(
        "global_load_dwordx4 %0, %4, off sc0 sc1\n\t"
        "global_load_dwordx4 %1, %4, off offset:16 sc0 sc1\n\t"
        "global_load_dwordx4 %2, %4, off offset:32 sc0 sc1\n\t"
        "global_load_dwordx4 %3, %4, off offset:48 sc0 sc1\n\t"
        "s_waitcnt vmcnt(0)"
        : "=&v"(a), "=&v"(b), "=&v"(c), "=&v"(d)
        : "v"(p)
        : "memory");
    v[0] = ((ull)a.y << 32) | a.x;
    v[1] = ((ull)a.w << 32) | a.z;
    v[2] = ((ull)b.y << 32) | b.x;
    v[3] = ((ull)b.w << 32) | b.z;
    v[4] = ((ull)c.y << 32) | c.x;
    v[5] = ((ull)c.w << 32) | c.z;
    v[6] = ((ull)d.y << 32) | d.x;
    v[7] = ((ull)d.w << 32) | d.z;
}

__global__ __launch_bounds__(256, 1)
void lstm_scan_kernel(const float* __restrict__ xg, const float* __restrict__ Wg,
                      const float* __restrict__ Rg, const float* __restrict__ bg_,
                      float* __restrict__ outg, ull* __restrict__ hbuf)
{
    __shared__ _Float16 xs[ROWS][XST];
    __shared__ _Float16 hs[ROWS][HST];
    __shared__ float    zs[128][ZST];   // [local col][row m]

    const int tid  = threadIdx.x;
    const int lane = tid & 63;
    const int wave = tid >> 6;
    const int bgi  = blockIdx.x & 7;   // batch group
    const int ngi  = blockIdx.x >> 3;  // u-slice group
    const int r0   = bgi * ROWS;
    const int u0   = ngi * USL;
    const int lj   = lane & 15;        // MFMA m/n index within tile
    const int lg   = lane >> 4;        // MFMA k-group

    // ---- one-time: build B fragments (W;R combined, fp16) in registers ----
    f16x8 bfr[2][KSTEPS];
#pragma unroll
    for (int nt2 = 0; nt2 < 2; ++nt2) {
        const int lc  = (wave * 2 + nt2) * 16 + lj;          // local col 0..127
        const int col = (lc >> 5) * 256 + u0 + (lc & 31);    // global col (gate*256+u)
#pragma unroll
        for (int ks = 0; ks < KSTEPS; ++ks) {
            f16x8 v;
#pragma unroll
            for (int i = 0; i < 8; ++i) {
                const int k = ks * 32 + lg * 8 + i;          // combined K index
                const float w = (k < FDIM) ? Wg[k * GCOLS + col]
                                           : Rg[(k - FDIM) * GCOLS + col];
                v[i] = (_Float16)w;
            }
            bfr[nt2][ks] = v;
        }
    }

    // staging / gate-update thread roles
    const int xrow = tid >> 4;          // row 0..15 (also gate row m)
    const int xf0  = (tid & 15) * 8;    // x chunk base (8 floats)
    const int hc0  = (tid & 15) * 16;   // h chunk base (16 fp16 = 8 words)
    const int uu0  = (tid * 2) & 31;    // first of 2 u columns this thread updates

    float bb[4][2];
#pragma unroll
    for (int gi = 0; gi < 4; ++gi) {
#pragma unroll
        for (int s = 0; s < 2; ++s)
            bb[gi][s] = bg_[gi * 256 + u0 + uu0 + s];
    }

    float cc0 = 0.f, cc1 = 0.f;   // cell state (2 elements per thread)

    for (int t = 0; t < T_STEPS; ++t) {
        const int p = t & 1;

        // x_t loads issued first: they complete under the sentinel spin
        const float* xp = xg + ((size_t)(r0 + xrow) * T_STEPS + (size_t)t) * FDIM + xf0;
        const f32x4 xa = *(const f32x4*)xp;
        const f32x4 xb = *(const f32x4*)(xp + 4);

        // ---- poll tagged h words: {lo32 = 2 fp16, hi32 = step tag} ----
        // t==0 reads the zeroed buffer (tag 0 == expected, h == 0).
        const ull* hp = hbuf + ((size_t)p * BATCH + r0 + xrow) * HWPR + (hc0 >> 1);
        ull hv[8];
        const unsigned tg = (unsigned)t;
        {
            // 1) sentinel spin on word 0 (1 load/retry + backoff: low L3 pressure)
            ull w0 = __hip_atomic_load(hp, __ATOMIC_RELAXED, __HIP_MEMORY_SCOPE_AGENT);
            while ((unsigned)(w0 >> 32) != tg) {
                __builtin_amdgcn_s_sleep(1);
                w0 = __hip_atomic_load(hp, __ATOMIC_RELAXED, __HIP_MEMORY_SCOPE_AGENT);
            }
            // 2) bulk wide fetch of all 8 words (one round trip)
            load_w8_asm(hp, hv);
            // 3) verify; any stale word -> known-good selective atomic reload
            while (true) {
                bool ok = true;
#pragma unroll
                for (int j = 0; j < 8; ++j)
                    ok &= ((unsigned)(hv[j] >> 32) == tg);
                if (ok) break;
#pragma unroll
                for (int j = 0; j < 8; ++j)
                    if ((unsigned)(hv[j] >> 32) != tg)
                        hv[j] = __hip_atomic_load(hp + j, __ATOMIC_RELAXED,
                                                  __HIP_MEMORY_SCOPE_AGENT);
            }
        }

        // stage x_t -> LDS fp16
        {
            f16x8 v;
#pragma unroll
            for (int i = 0; i < 4; ++i) { v[i] = (_Float16)xa[i]; v[4 + i] = (_Float16)xb[i]; }
            *(f16x8*)&xs[xrow][xf0] = v;
        }
        // stage h -> LDS (already fp16 in the word lo32s, just repack)
        {
            uint4 a, b2;
            a.x = (unsigned)hv[0]; a.y = (unsigned)hv[1];
            a.z = (unsigned)hv[2]; a.w = (unsigned)hv[3];
            b2.x = (unsigned)hv[4]; b2.y = (unsigned)hv[5];
            b2.z = (unsigned)hv[6]; b2.w = (unsigned)hv[7];
            *(uint4*)&hs[xrow][hc0]     = a;
            *(uint4*)&hs[xrow][hc0 + 8] = b2;
        }
        __syncthreads();

        // z = [x_t | h] @ [W;R] slice : 12 K-steps, 2 n-tiles per wave
        f32x4 acc0 = {0.f, 0.f, 0.f, 0.f};
        f32x4 acc1 = {0.f, 0.f, 0.f, 0.f};
#pragma unroll
        for (int ks = 0; ks < KSTEPS; ++ks) {
            const f16x8 a = (ks < 4)
                ? *(const f16x8*)&xs[lj][ks * 32 + lg * 8]
                : *(const f16x8*)&hs[lj][(ks - 4) * 32 + lg * 8];
            acc0 = __builtin_amdgcn_mfma_f32_16x16x32_f16(a, bfr[0][ks], acc0, 0, 0, 0);
            acc1 = __builtin_amdgcn_mfma_f32_16x16x32_f16(a, bfr[1][ks], acc1, 0, 0, 0);
        }
        // scatter z fragments to LDS (col-major, 16B-contiguous rows per col)
        {
            const int lc0 = wave * 32 + lj;
            *(f32x4*)&zs[lc0][lg * 4]      = acc0;   // rows lg*4..lg*4+3, col lc0
            *(f32x4*)&zs[lc0 + 16][lg * 4] = acc1;
        }
        __syncthreads();

        // gate math: each thread owns (m=xrow, uu0) and (m, uu0+1)
        float hv0, hv1;
        {
            const int m = xrow;
            float i0 = zs[0 * 32 + uu0][m] + bb[0][0];
            float f0 = zs[1 * 32 + uu0][m] + bb[1][0];
            float g0 = zs[2 * 32 + uu0][m] + bb[2][0];
            float o0 = zs[3 * 32 + uu0][m] + bb[3][0];
            float i1 = zs[0 * 32 + uu0 + 1][m] + bb[0][1];
            float f1 = zs[1 * 32 + uu0 + 1][m] + bb[1][1];
            float g1 = zs[2 * 32 + uu0 + 1][m] + bb[2][1];
            float o1 = zs[3 * 32 + uu0 + 1][m] + bb[3][1];
            i0 = 1.f / (1.f + __expf(-i0));
            f0 = 1.f / (1.f + __expf(-f0));
            o0 = 1.f / (1.f + __expf(-o0));
            i1 = 1.f / (1.f + __expf(-i1));
            f1 = 1.f / (1.f + __expf(-f1));
            o1 = 1.f / (1.f + __expf(-o1));
            cc0 = f0 * cc0 + i0 * g0;      // g is LINEAR (activation=None)
            cc1 = f1 * cc1 + i1 * g1;
            hv0 = o0 * cc0;                // h = o * c (no tanh on cell)
            hv1 = o1 * cc1;
        }

        if (t == T_STEPS - 1) {
            float* op = outg + (size_t)(r0 + xrow) * UDIM + u0 + uu0;
            op[0] = tanhf(hv0);            // post-hoc tanh on last h
            op[1] = tanhf(hv1);
        } else {
            // publish h as ONE tagged 64-bit atomic word: no fence, no counter
            union { _Float16 h[2]; unsigned lo; } pk;
            pk.h[0] = (_Float16)hv0;
            pk.h[1] = (_Float16)hv1;
            const ull w =
                ((ull)(unsigned)(t + 1) << 32) | pk.lo;
            ull* hw =
                hbuf + ((size_t)(p ^ 1) * BATCH + r0 + xrow) * HWPR + ((u0 + uu0) >> 1);
            __hip_atomic_store(hw, w, __ATOMIC_RELAXED, __HIP_MEMORY_SCOPE_AGENT);
        }
    }
}

extern "C" void kernel_launch(void* const* d_in, const int* in_sizes, int n_in,
                              void* d_out, int out_size, void* d_ws, size_t ws_size,
                              hipStream_t stream) {
    const float* x = (const float*)d_in[0];   // [128,1024,128]
    const float* W = (const float*)d_in[1];   // [128,1024]
    const float* R = (const float*)d_in[2];   // [256,1024]
    const float* b = (const float*)d_in[3];   // [1024]
    float* out = (float*)d_out;               // [128,256]

    ull* hbuf = (ull*)d_ws;                   // [2][128][128] tagged words

    // zero tags every launch (tag 0 == "h ready for step 0", h == 0)
    const size_t clr = (size_t)2 * BATCH * HWPR * sizeof(ull);
    hipMemsetAsync(d_ws, 0, clr, stream);

    hipLaunchKernelGGL(lstm_scan_kernel, dim3(64), dim3(256), 0, stream,
                       x, W, R, b, out, hbuf);
}

// Round 10
// 1810.218 us; speedup vs baseline: 9.5089x; 1.1454x over previous
//
#include <hip/hip_runtime.h>

typedef __attribute__((ext_vector_type(8))) _Float16 f16x8;
typedef __attribute__((ext_vector_type(4))) float f32x4;
typedef __attribute__((ext_vector_type(4))) unsigned u32x4;
typedef unsigned long long ull;

#define T_STEPS 1024
#define BATCH   128
#define FDIM    128
#define UDIM    256
#define GCOLS   1024   // 4*U
#define NGRP    8      // WGs per batch-group (u-split)
#define ROWS    16     // batch rows per WG
#define USL     32     // u columns per WG
#define KSTEPS  12     // 384 / 32
#define HWPR    128    // h words per row (256 fp16 / 2)
#define XST     136    // x stage row stride (f16), 128+8 pad
#define HST     264    // h stage row stride (f16), 256+8 pad
#define ZST     18     // zs col stride (f32): write banks 18*lj mod 32 -> 16
                       // distinct; read banks 4*(tid&15)+m mod 32 -> 2-way

// One-round-trip fetch of 8 tagged words (device-coherent sc0 sc1).
__device__ __forceinline__ void load_w8_asm(const ull* p, ull* v) {
    u32x4 a, b, c, d;
    asm volatile(
        "global_load_dwordx4 %0, %4, off sc0 sc1\n\t"
        "global_load_dwordx4 %1, %4, off offset:16 sc0 sc1\n\t"
        "global_load_dwordx4 %2, %4, off offset:32 sc0 sc1\n\t"
        "global_load_dwordx4 %3, %4, off offset:48 sc0 sc1\n\t"
        "s_waitcnt vmcnt(0)"
        : "=&v"(a), "=&v"(b), "=&v"(c), "=&v"(d)
        : "v"(p)
        : "memory");
    v[0] = ((ull)a.y << 32) | a.x;
    v[1] = ((ull)a.w << 32) | a.z;
    v[2] = ((ull)b.y << 32) | b.x;
    v[3] = ((ull)b.w << 32) | b.z;
    v[4] = ((ull)c.y << 32) | c.x;
    v[5] = ((ull)c.w << 32) | c.z;
    v[6] = ((ull)d.y << 32) | d.x;
    v[7] = ((ull)d.w << 32) | d.z;
}

__global__ __launch_bounds__(256, 1)
void lstm_scan_kernel(const float* __restrict__ xg, const float* __restrict__ Wg,
                      const float* __restrict__ Rg, const float* __restrict__ bg_,
                      float* __restrict__ outg, ull* __restrict__ hbuf)
{
    __shared__ _Float16 xs[ROWS][XST];
    __shared__ _Float16 hs[ROWS][HST];
    __shared__ float    zs[128][ZST];   // [local col][row m]

    const int tid  = threadIdx.x;
    const int lane = tid & 63;
    const int wave = tid >> 6;
    const int bgi  = blockIdx.x & 7;   // batch group
    const int ngi  = blockIdx.x >> 3;  // u-slice group
    const int r0   = bgi * ROWS;
    const int u0   = ngi * USL;
    const int lj   = lane & 15;        // MFMA m/n index within tile
    const int lg   = lane >> 4;        // MFMA k-group

    // ---- one-time: build B fragments (W;R combined, fp16) in registers ----
    f16x8 bfr[2][KSTEPS];
#pragma unroll
    for (int nt2 = 0; nt2 < 2; ++nt2) {
        const int lc  = (wave * 2 + nt2) * 16 + lj;          // local col 0..127
        const int col = (lc >> 5) * 256 + u0 + (lc & 31);    // global col (gate*256+u)
#pragma unroll
        for (int ks = 0; ks < KSTEPS; ++ks) {
            f16x8 v;
#pragma unroll
            for (int i = 0; i < 8; ++i) {
                const int k = ks * 32 + lg * 8 + i;          // combined K index
                const float w = (k < FDIM) ? Wg[k * GCOLS + col]
                                           : Rg[(k - FDIM) * GCOLS + col];
                v[i] = (_Float16)w;
            }
            bfr[nt2][ks] = v;
        }
    }

    // staging / gate-update thread roles
    const int xrow = tid >> 4;          // row 0..15 (also gate row m)
    const int xf0  = (tid & 15) * 8;    // x chunk base (8 floats)
    const int hc0  = (tid & 15) * 16;   // h chunk base (16 fp16 = 8 words)
    const int uu0  = (tid * 2) & 31;    // first of 2 u columns this thread updates

    float bb[4][2];
#pragma unroll
    for (int gi = 0; gi < 4; ++gi) {
#pragma unroll
        for (int s = 0; s < 2; ++s)
            bb[gi][s] = bg_[gi * 256 + u0 + uu0 + s];
    }

    float cc0 = 0.f, cc1 = 0.f;   // cell state (2 elements per thread)

    for (int t = 0; t < T_STEPS; ++t) {
        const int p = t & 1;

        // x_t loads issued first: they complete under the poll
        const float* xp = xg + ((size_t)(r0 + xrow) * T_STEPS + (size_t)t) * FDIM + xf0;
        const f32x4 xa = *(const f32x4*)xp;
        const f32x4 xb = *(const f32x4*)(xp + 4);

        // ---- poll tagged h words: {lo32 = 2 fp16, hi32 = step tag} ----
        // Fused wide poll: ONE L3 round trip from ready to data.
        // t==0 reads the zeroed buffer (tag 0 == expected, h == 0).
        const ull* hp = hbuf + ((size_t)p * BATCH + r0 + xrow) * HWPR + (hc0 >> 1);
        ull hv[8];
        const unsigned tg = (unsigned)t;
        {
            load_w8_asm(hp, hv);
            while (true) {
                bool ok = true;
#pragma unroll
                for (int j = 0; j < 8; ++j)
                    ok &= ((unsigned)(hv[j] >> 32) == tg);
                if (ok) break;
                __builtin_amdgcn_s_sleep(1);   // backoff: keep L3 pressure low
                load_w8_asm(hp, hv);
            }
        }

        // stage x_t -> LDS fp16
        {
            f16x8 v;
#pragma unroll
            for (int i = 0; i < 4; ++i) { v[i] = (_Float16)xa[i]; v[4 + i] = (_Float16)xb[i]; }
            *(f16x8*)&xs[xrow][xf0] = v;
        }
        // stage h -> LDS (already fp16 in the word lo32s, just repack)
        {
            uint4 a, b2;
            a.x = (unsigned)hv[0]; a.y = (unsigned)hv[1];
            a.z = (unsigned)hv[2]; a.w = (unsigned)hv[3];
            b2.x = (unsigned)hv[4]; b2.y = (unsigned)hv[5];
            b2.z = (unsigned)hv[6]; b2.w = (unsigned)hv[7];
            *(uint4*)&hs[xrow][hc0]     = a;
            *(uint4*)&hs[xrow][hc0 + 8] = b2;
        }
        __syncthreads();

        // z = [x_t | h] @ [W;R] slice : 12 K-steps, 2 n-tiles per wave
        f32x4 acc0 = {0.f, 0.f, 0.f, 0.f};
        f32x4 acc1 = {0.f, 0.f, 0.f, 0.f};
#pragma unroll
        for (int ks = 0; ks < KSTEPS; ++ks) {
            const f16x8 a = (ks < 4)
                ? *(const f16x8*)&xs[lj][ks * 32 + lg * 8]
                : *(const f16x8*)&hs[lj][(ks - 4) * 32 + lg * 8];
            acc0 = __builtin_amdgcn_mfma_f32_16x16x32_f16(a, bfr[0][ks], acc0, 0, 0, 0);
            acc1 = __builtin_amdgcn_mfma_f32_16x16x32_f16(a, bfr[1][ks], acc1, 0, 0, 0);
        }
        // scatter z fragments to LDS (col-major, b64 writes, conflict-free)
        {
            const int lc0 = wave * 32 + lj;
            float2 w01, w23;
            w01.x = acc0[0]; w01.y = acc0[1]; w23.x = acc0[2]; w23.y = acc0[3];
            *(float2*)&zs[lc0][lg * 4]     = w01;
            *(float2*)&zs[lc0][lg * 4 + 2] = w23;
            w01.x = acc1[0]; w01.y = acc1[1]; w23.x = acc1[2]; w23.y = acc1[3];
            *(float2*)&zs[lc0 + 16][lg * 4]     = w01;
            *(float2*)&zs[lc0 + 16][lg * 4 + 2] = w23;
        }
        __syncthreads();

        // gate math: each thread owns (m=xrow, uu0) and (m, uu0+1)
        float hv0, hv1;
        {
            const int m = xrow;
            float i0 = zs[0 * 32 + uu0][m] + bb[0][0];
            float f0 = zs[1 * 32 + uu0][m] + bb[1][0];
            float g0 = zs[2 * 32 + uu0][m] + bb[2][0];
            float o0 = zs[3 * 32 + uu0][m] + bb[3][0];
            float i1 = zs[0 * 32 + uu0 + 1][m] + bb[0][1];
            float f1 = zs[1 * 32 + uu0 + 1][m] + bb[1][1];
            float g1 = zs[2 * 32 + uu0 + 1][m] + bb[2][1];
            float o1 = zs[3 * 32 + uu0 + 1][m] + bb[3][1];
            i0 = 1.f / (1.f + __expf(-i0));
            f0 = 1.f / (1.f + __expf(-f0));
            o0 = 1.f / (1.f + __expf(-o0));
            i1 = 1.f / (1.f + __expf(-i1));
            f1 = 1.f / (1.f + __expf(-f1));
            o1 = 1.f / (1.f + __expf(-o1));
            cc0 = f0 * cc0 + i0 * g0;      // g is LINEAR (activation=None)
            cc1 = f1 * cc1 + i1 * g1;
            hv0 = o0 * cc0;                // h = o * c (no tanh on cell)
            hv1 = o1 * cc1;
        }

        if (t == T_STEPS - 1) {
            float* op = outg + (size_t)(r0 + xrow) * UDIM + u0 + uu0;
            op[0] = tanhf(hv0);            // post-hoc tanh on last h
            op[1] = tanhf(hv1);
        } else {
            // publish h as ONE tagged 64-bit atomic word: no fence, no counter
            union { _Float16 h[2]; unsigned lo; } pk;
            pk.h[0] = (_Float16)hv0;
            pk.h[1] = (_Float16)hv1;
            const ull w =
                ((ull)(unsigned)(t + 1) << 32) | pk.lo;
            ull* hw =
                hbuf + ((size_t)(p ^ 1) * BATCH + r0 + xrow) * HWPR + ((u0 + uu0) >> 1);
            __hip_atomic_store(hw, w, __ATOMIC_RELAXED, __HIP_MEMORY_SCOPE_AGENT);
        }
    }
}

extern "C" void kernel_launch(void* const* d_in, const int* in_sizes, int n_in,
                              void* d_out, int out_size, void* d_ws, size_t ws_size,
                              hipStream_t stream) {
    const float* x = (const float*)d_in[0];   // [128,1024,128]
    const float* W = (const float*)d_in[1];   // [128,1024]
    const float* R = (const float*)d_in[2];   // [256,1024]
    const float* b = (const float*)d_in[3];   // [1024]
    float* out = (float*)d_out;               // [128,256]

    ull* hbuf = (ull*)d_ws;                   // [2][128][128] tagged words

    // zero tags every launch (tag 0 == "h ready for step 0", h == 0)
    const size_t clr = (size_t)2 * BATCH * HWPR * sizeof(ull);
    hipMemsetAsync(d_ws, 0, clr, stream);

    hipLaunchKernelGGL(lstm_scan_kernel, dim3(64), dim3(256), 0, stream,
                       x, W, R, b, out, hbuf);
}

// Round 11
// 1690.164 us; speedup vs baseline: 10.1843x; 1.0710x over previous
//
#include <hip/hip_runtime.h>

typedef __attribute__((ext_vector_type(8))) _Float16 f16x8;
typedef __attribute__((ext_vector_type(4))) float f32x4;
typedef __attribute__((ext_vector_type(4))) unsigned u32x4;
typedef unsigned long long ull;

#define T_STEPS 1024
#define BATCH   128
#define FDIM    128
#define UDIM    256
#define GCOLS   1024   // 4*U
#define ROWS    16     // batch rows per group
#define HWPR    128    // h words per row (256 fp16 / 2)
#define XST     136    // x stage row stride (f16)
#define HST     264    // h stage row stride (f16)

// Protocol: tagged 64-bit words {lo32: 2 fp16 h, hi32: step tag}, double-
// buffered, relaxed agent-scope; fused wide poll (r10). Structure: x.W MFMAs
// overlap the poll RT; in-wave gate combine (r5/r8); ONE barrier per step.

__global__ __launch_bounds__(256, 1)
void lstm_scan_kernel(const float* __restrict__ xg, const float* __restrict__ Wg,
                      const float* __restrict__ Rg, const float* __restrict__ bg_,
                      float* __restrict__ outg, ull* __restrict__ hbuf)
{
    __shared__ _Float16 xs[2][ROWS][XST];
    __shared__ _Float16 hs[2][ROWS][HST];

    const int tid  = threadIdx.x;
    const int lane = tid & 63;
    const int wv   = tid >> 6;
    const int bgi  = blockIdx.x & 7;    // batch group
    const int ngi  = blockIdx.x >> 3;   // u-slice group
    const int r0   = bgi * ROWS;
    const int u0   = ngi * 32;
    const int lj   = lane & 15;         // MFMA m/n index
    const int lg   = lane >> 4;         // MFMA k-group
    const int hb   = lj >> 3;           // gate-half owner bit
    const int uc   = u0 + wv * 8 + (lj & 7);   // this lane's u column

    // ---- one-time: B fragments, in-wave mapping (wave owns 4 gates x 8 ucols)
    f16x8 bfr[2][12];
#pragma unroll
    for (int nt = 0; nt < 2; ++nt) {
        const int col = (nt * 2 + hb) * 256 + uc;
#pragma unroll
        for (int ks = 0; ks < 12; ++ks) {
            f16x8 v;
#pragma unroll
            for (int i = 0; i < 8; ++i) {
                const int k = ks * 32 + lg * 8 + i;
                const float w = (k < FDIM) ? Wg[k * GCOLS + col]
                                           : Rg[(k - FDIM) * GCOLS + col];
                v[i] = (_Float16)w;
            }
            bfr[nt][ks] = v;
        }
    }

    const float b_i = bg_[uc];
    const float b_f = bg_[256 + uc];
    const float b_g = bg_[512 + uc];
    const float b_o = bg_[768 + uc];

    const int row0 = lg * 4 + hb * 2;   // first of this lane's 2 output rows
    float cc0 = 0.f, cc1 = 0.f;

    // staging/poll roles (r10): thread (xrow, chunk) owns 8 words of row xrow
    const int xrow = tid >> 4;
    const int xf0  = (tid & 15) * 8;    // x chunk base (8 floats / 8 fp16)
    const int hc0  = (tid & 15) * 16;   // h chunk base (16 fp16 = 8 words)
    const size_t hrd = (size_t)(r0 + xrow) * HWPR + (hc0 >> 1);
    const float* const xps = xg + (size_t)(r0 + xrow) * T_STEPS * FDIM + xf0;

    // prologue: stage x0 into xs[0]; preload x1
    {
        const f32x4 xa = *(const f32x4*)xps;
        const f32x4 xb = *(const f32x4*)(xps + 4);
        f16x8 v;
#pragma unroll
        for (int i = 0; i < 4; ++i) { v[i] = (_Float16)xa[i]; v[4 + i] = (_Float16)xb[i]; }
        *(f16x8*)&xs[0][xrow][xf0] = v;
    }
    f32x4 xn0 = *(const f32x4*)(xps + FDIM);
    f32x4 xn1 = *(const f32x4*)(xps + FDIM + 4);
    __syncthreads();

    for (int t = 0; t < T_STEPS; ++t) {
        const int p = t & 1;
        const ull* hp = hbuf + (size_t)p * BATCH * HWPR + hrd;
        const unsigned tg = (unsigned)t;

        // ---- B: issue wide poll, NO wait (poisoned tags: a skewed vmcnt can
        // only force a retry, never a false pass) ----
        u32x4 pa = {0u, 0xFFFFFFFFu, 0u, 0xFFFFFFFFu};
        u32x4 pb = pa, pc = pa, pd = pa;
        asm volatile(
            "global_load_dwordx4 %0, %4, off sc0 sc1\n\t"
            "global_load_dwordx4 %1, %4, off offset:16 sc0 sc1\n\t"
            "global_load_dwordx4 %2, %4, off offset:32 sc0 sc1\n\t"
            "global_load_dwordx4 %3, %4, off offset:48 sc0 sc1"
            : "+v"(pa), "+v"(pb), "+v"(pc), "+v"(pd)
            : "v"(hp)
            : "memory");

        // ---- A: stage x_{t+1} -> xs[p^1] (regs loaded last step) ----
        {
            f16x8 v;
#pragma unroll
            for (int i = 0; i < 4; ++i) { v[i] = (_Float16)xn0[i]; v[4 + i] = (_Float16)xn1[i]; }
            *(f16x8*)&xs[p ^ 1][xrow][xf0] = v;
        }
        // ---- A': issue x_{t+2} loads (exactly 2 vmem behind the 4 poll loads)
        {
            const int tn = (t + 2 < T_STEPS) ? (t + 2) : (T_STEPS - 1);
            xn0 = *(const f32x4*)(xps + (size_t)tn * FDIM);
            xn1 = *(const f32x4*)(xps + (size_t)tn * FDIM + 4);
        }

        // ---- C: x.W MFMAs from xs[p] — overlaps the poll round trip ----
        f32x4 a0e = {0,0,0,0}, a0o = {0,0,0,0}, a1e = {0,0,0,0}, a1o = {0,0,0,0};
#pragma unroll
        for (int ks = 0; ks < 4; ++ks) {
            const f16x8 a = *(const f16x8*)&xs[p][lj][ks * 32 + lg * 8];
            if (ks & 1) {
                a0o = __builtin_amdgcn_mfma_f32_16x16x32_f16(a, bfr[0][ks], a0o, 0, 0, 0);
                a1o = __builtin_amdgcn_mfma_f32_16x16x32_f16(a, bfr[1][ks], a1o, 0, 0, 0);
            } else {
                a0e = __builtin_amdgcn_mfma_f32_16x16x32_f16(a, bfr[0][ks], a0e, 0, 0, 0);
                a1e = __builtin_amdgcn_mfma_f32_16x16x32_f16(a, bfr[1][ks], a1e, 0, 0, 0);
            }
        }

        // ---- D: wait poll loads only (the 2 x loads keep flying), check tags
        asm volatile("s_waitcnt vmcnt(2)" ::: "memory");
        __builtin_amdgcn_sched_barrier(0);
        while (!((pa.y == tg) & (pa.w == tg) & (pb.y == tg) & (pb.w == tg) &
                 (pc.y == tg) & (pc.w == tg) & (pd.y == tg) & (pd.w == tg))) {
            __builtin_amdgcn_s_sleep(1);
            asm volatile(
                "global_load_dwordx4 %0, %4, off sc0 sc1\n\t"
                "global_load_dwordx4 %1, %4, off offset:16 sc0 sc1\n\t"
                "global_load_dwordx4 %2, %4, off offset:32 sc0 sc1\n\t"
                "global_load_dwordx4 %3, %4, off offset:48 sc0 sc1\n\t"
                "s_waitcnt vmcnt(0)"
                : "=&v"(pa), "=&v"(pb), "=&v"(pc), "=&v"(pd)
                : "v"(hp)
                : "memory");
            __builtin_amdgcn_sched_barrier(0);
        }

        // ---- E: stage h -> hs[p] (fp16 payloads are the word lo32s) ----
        {
            uint4 q0, q1;
            q0.x = pa.x; q0.y = pa.z; q0.z = pb.x; q0.w = pb.z;
            q1.x = pc.x; q1.y = pc.z; q1.z = pd.x; q1.w = pd.z;
            *(uint4*)&hs[p][xrow][hc0]     = q0;
            *(uint4*)&hs[p][xrow][hc0 + 8] = q1;
        }
        __syncthreads();   // F: the ONLY barrier per step

        // ---- G: h.R MFMAs ----
#pragma unroll
        for (int ks = 4; ks < 12; ++ks) {
            const f16x8 a = *(const f16x8*)&hs[p][lj][(ks - 4) * 32 + lg * 8];
            if (ks & 1) {
                a0o = __builtin_amdgcn_mfma_f32_16x16x32_f16(a, bfr[0][ks], a0o, 0, 0, 0);
                a1o = __builtin_amdgcn_mfma_f32_16x16x32_f16(a, bfr[1][ks], a1o, 0, 0, 0);
            } else {
                a0e = __builtin_amdgcn_mfma_f32_16x16x32_f16(a, bfr[0][ks], a0e, 0, 0, 0);
                a1e = __builtin_amdgcn_mfma_f32_16x16x32_f16(a, bfr[1][ks], a1e, 0, 0, 0);
            }
        }
        const f32x4 z0 = a0e + a0o;   // gates i,f
        const f32x4 z1 = a1e + a1o;   // gates g,o

        // ---- H: in-wave gate combine (partner lane^8 holds the other gate)
        float s0[4], s1[4];
#pragma unroll
        for (int e = 0; e < 4; ++e) {
            s0[e] = __shfl_xor(z0[e], 8);
            s1[e] = __shfl_xor(z1[e], 8);
        }
        float zi0 = hb ? s0[2] : z0[0];
        float zi1 = hb ? s0[3] : z0[1];
        float zf0 = hb ? z0[2] : s0[0];
        float zf1 = hb ? z0[3] : s0[1];
        float zg0 = hb ? s1[2] : z1[0];
        float zg1 = hb ? s1[3] : z1[1];
        float zo0 = hb ? z1[2] : s1[0];
        float zo1 = hb ? z1[3] : s1[1];

        zi0 += b_i; zi1 += b_i; zf0 += b_f; zf1 += b_f;
        zg0 += b_g; zg1 += b_g; zo0 += b_o; zo1 += b_o;

        const float i0 = 1.f / (1.f + __expf(-zi0));
        const float f0 = 1.f / (1.f + __expf(-zf0));
        const float o0 = 1.f / (1.f + __expf(-zo0));
        const float i1 = 1.f / (1.f + __expf(-zi1));
        const float f1 = 1.f / (1.f + __expf(-zf1));
        const float o1 = 1.f / (1.f + __expf(-zo1));
        cc0 = f0 * cc0 + i0 * zg0;     // g is LINEAR (activation=None)
        cc1 = f1 * cc1 + i1 * zg1;
        const float h0v = o0 * cc0;    // h = o * c (no tanh on cell)
        const float h1v = o1 * cc1;

        // ---- I: publish / output ----
        if (t == T_STEPS - 1) {
            float* op = outg + (size_t)(r0 + row0) * UDIM + uc;
            op[0]    = tanhf(h0v);     // post-hoc tanh on last h
            op[UDIM] = tanhf(h1v);
        } else {
            const float n0 = __shfl_xor(h0v, 1);
            const float n1 = __shfl_xor(h1v, 1);
            if (!(lj & 1)) {
                union { _Float16 h[2]; unsigned lo; } qa, qb;
                qa.h[0] = (_Float16)h0v; qa.h[1] = (_Float16)n0;
                qb.h[0] = (_Float16)h1v; qb.h[1] = (_Float16)n1;
                const ull tagw = (ull)(unsigned)(t + 1) << 32;
                ull* hw = hbuf + (size_t)(p ^ 1) * BATCH * HWPR
                          + (size_t)(r0 + row0) * HWPR + (uc >> 1);
                __hip_atomic_store(hw,        tagw | qa.lo,
                                   __ATOMIC_RELAXED, __HIP_MEMORY_SCOPE_AGENT);
                __hip_atomic_store(hw + HWPR, tagw | qb.lo,
                                   __ATOMIC_RELAXED, __HIP_MEMORY_SCOPE_AGENT);
            }
        }
    }
}

extern "C" void kernel_launch(void* const* d_in, const int* in_sizes, int n_in,
                              void* d_out, int out_size, void* d_ws, size_t ws_size,
                              hipStream_t stream) {
    const float* x = (const float*)d_in[0];   // [128,1024,128]
    const float* W = (const float*)d_in[1];   // [128,1024]
    const float* R = (const float*)d_in[2];   // [256,1024]
    const float* b = (const float*)d_in[3];   // [1024]
    float* out = (float*)d_out;               // [128,256]

    ull* hbuf = (ull*)d_ws;                   // [2][128][128] tagged words

    // zero tags every launch (tag 0 == "h ready for step 0", h == 0)
    const size_t clr = (size_t)2 * BATCH * HWPR * sizeof(ull);
    hipMemsetAsync(d_ws, 0, clr, stream);

    hipLaunchKernelGGL(lstm_scan_kernel, dim3(64), dim3(256), 0, stream,
                       x, W, R, b, out, hbuf);
}